// Round 8
// baseline (19.356 us; speedup 1.0000x reference)
//
#include <hip/hip_runtime.h>
#include <hip/hip_bf16.h>
#include <math.h>

#define NCELL 32
#define P 128
#define C 4
#define KSEL 64
#define THRESH 0.7f
#define NEGV -1e9f

#define FMA4(acc, av, bv)                                                     \
  acc.x += av.x * bv.x; acc.y += av.y * bv.y;                                 \
  acc.z += av.z * bv.z; acc.w += av.w * bv.w

__device__ __forceinline__ float hsum4(float4 v) {
  return (v.x + v.y) + (v.z + v.w);
}

// Physical LDS row map (stride 132 floats):
//  0..15  K(c,m)   16..19 KB(m)
// 20..35  V(d,n)   36..39 VB(n)
// 40..55  Q(c,m)   56..59 QB(m)
// 60..63  WM(n)  (masked w_w)
#define RSTRIDE 132
#define NROWS 64

__global__ __launch_bounds__(256) void pillar_attn_sample_kernel(
    const float* __restrict__ pts,      // [NCELL][P][C]
    const void*  __restrict__ maskp,    // [NCELL][P]  (dtype sniffed)
    const float* __restrict__ pos,      // [P][C]
    const float* __restrict__ q_w, const float* __restrict__ q_b,
    const float* __restrict__ k_w, const float* __restrict__ k_b,
    const float* __restrict__ v_w, const float* __restrict__ v_b,
    const float* __restrict__ w_w, const float* __restrict__ w_b,
    float* __restrict__ out)            // [NCELL*KSEL*C] ++ [NCELL*KSEL]
{
  __shared__ __align__(16) float rowsF[NROWS * RSTRIDE];
  __shared__ __align__(16) float sRp[800];   // KV Gram k-half partials [h][Kside 20][Vside 20]
  __shared__ __align__(16) float sGp[160];   // Qside.WM k-half partials [h][qrow 20][n 4]
  __shared__ float sVSs[16];                 // V row sums
  __shared__ float sVBs[4];                  // VB row sums
  __shared__ float sWUp[8];                  // WU wave-partials [wave][2]
  __shared__ __align__(16) float sC[36];     // 35 cubic monomial coeffs (+pad)
  __shared__ __align__(16) float sC2[8];     // 5 t2 coeffs (+pad)
  __shared__ __align__(16) float4 sPts[P];
  __shared__ float wbuf[P];
  __shared__ unsigned long long sBM[2];      // sel ballots
  __shared__ unsigned long long sMM[2];      // mask ballots
  __shared__ int slotp[KSEL];

  const int cell = blockIdx.x;
  const int t = threadIdx.x;

  // ---- mask dtype detection (uniform) ----
  int mkind;
  {
    const unsigned* u = (const unsigned*)maskp;
    bool i32ok = true, f32ok = true;
    #pragma unroll
    for (int k = 0; k < 8; ++k) {
      unsigned v = u[k];
      if (v != 0u && v != 1u) i32ok = false;
      if (v != 0u && v != 0x3f800000u) f32ok = false;
    }
    mkind = (i32ok || f32ok) ? 0 : 1;
  }

  // ---- own mask bit (element t&127) ----
  bool mv_self;
  {
    int i = t & 127;
    if (mkind == 0) mv_self = ((const unsigned*)maskp)[cell * P + i] != 0u;
    else            mv_self = ((const unsigned char*)maskp)[cell * P + i] != 0;
  }
  const bool mv = mv_self;

  // ---- early global loads ----
  float4 pv4, po4;
  float wb0 = w_b[0];
  if (t < P) {
    pv4 = ((const float4*)pts)[cell * P + t];
    po4 = ((const float4*)pos)[t];
  }

  // ---- staging: rows into LDS + register captures for shuffle sums ----
  const float4* q4 = (const float4*)q_w;
  const float4* k4 = (const float4*)k_w;
  const float4* v4 = (const float4*)v_w;
  int g0 = t, g1 = t + 256;
  float4 k0 = k4[g0], k1 = k4[g1];
  float4 v0 = v4[g0], v1 = v4[g1];
  float4 q0 = q4[g0], q1 = q4[g1];
  float ww1 = w_w[t], ww2 = w_w[t + 256];
  {
    int r = g0 >> 5, ch = g0 & 31;
    ((float4*)(rowsF + r * RSTRIDE))[ch] = k0;
    ((float4*)(rowsF + (20 + r) * RSTRIDE))[ch] = v0;
    ((float4*)(rowsF + (40 + r) * RSTRIDE))[ch] = q0;
  }
  {
    int r = g1 >> 5, ch = g1 & 31;           // r in 8..15
    ((float4*)(rowsF + r * RSTRIDE))[ch] = k1;
    ((float4*)(rowsF + (20 + r) * RSTRIDE))[ch] = v1;
    ((float4*)(rowsF + (40 + r) * RSTRIDE))[ch] = q1;
  }
  float vbs = 0.f;
  if (t < 128) {
    int r = t >> 5, ch = t & 31;
    ((float4*)(rowsF + (16 + r) * RSTRIDE))[ch] = ((const float4*)k_b)[t];
  } else {
    int u = t - 128; int r = u >> 5, ch = u & 31;
    float4 vb = ((const float4*)v_b)[u];
    ((float4*)(rowsF + (36 + r) * RSTRIDE))[ch] = vb;
    ((float4*)(rowsF + (56 + r) * RSTRIDE))[ch] = ((const float4*)q_b)[u];
    vbs = hsum4(vb);
  }
  // masked w_w rows 60..63 (one own mask bit serves elements t and t+256)
  rowsF[(60 + (t >> 7)) * RSTRIDE + (t & 127)] = mv_self ? ww1 : 0.f;
  rowsF[(62 + (t >> 7)) * RSTRIDE + (t & 127)] = mv_self ? ww2 : 0.f;
  if (t < 128) sPts[t] = pv4;

  // ---- shuffle reductions: VS (32-group), VBs (32-group), WU (full wave) ----
  {
    const int w = t >> 6, L = t & 63;
    float s0 = hsum4(v0), s1 = hsum4(v1);
    float u0 = mv_self ? 0.f : ww1, u1 = mv_self ? 0.f : ww2;
    #pragma unroll
    for (int m = 1; m <= 16; m <<= 1) {
      s0 += __shfl_xor(s0, m); s1 += __shfl_xor(s1, m);
    }
    #pragma unroll
    for (int m = 1; m <= 32; m <<= 1) {
      u0 += __shfl_xor(u0, m); u1 += __shfl_xor(u1, m);
    }
    if (t >= 128) {
      #pragma unroll
      for (int m = 1; m <= 16; m <<= 1) vbs += __shfl_xor(vbs, m);
    }
    if ((L & 31) == 0) {
      int half = L >> 5;
      sVSs[2 * w + half]     = s0;           // V rows 0..7
      sVSs[8 + 2 * w + half] = s1;           // V rows 8..15
      if (t >= 128) sVBs[(w - 2) * 2 + half] = vbs;
    }
    if (L == 0) { sWUp[w * 2] = u0; sWUp[w * 2 + 1] = u1; }
  }
  if (t < P) {
    unsigned long long mm = __ballot(mv);
    if ((t & 63) == 0) sMM[t >> 6] = mm;
  }
  __syncthreads();   // S0: rows, sPts, partial sums, ballots ready

  // ---- dot phase: 240 uniform k-half 2x2 tile units (64 ds_read_b128 each) ----
  if (t < 240) {
    int pa0, pa1, pb0, pb1, h;
    float *o00, *o01, *o10, *o11;
    if (t < 200) {                       // KV Gram k-half tiles
      int tile = t >> 1; h = t & 1;
      int up = tile / 10, vq = tile % 10;
      pa0 = up;      pa1 = up + 10;
      pb0 = 20 + vq; pb1 = 30 + vq;
      float* base = sRp + h * 400;
      o00 = base + up * 20 + vq;        o01 = base + up * 20 + vq + 10;
      o10 = base + (up + 10) * 20 + vq; o11 = base + (up + 10) * 20 + vq + 10;
    } else {                             // Qside x WM k-half tiles
      int u2 = t - 200; int tile = u2 >> 1; h = u2 & 1;
      int p = tile >> 1, nb = (tile & 1) * 2;
      pa0 = 40 + p;  pa1 = 50 + p;
      pb0 = 60 + nb; pb1 = 61 + nb;
      float* base = sGp + h * 80;
      o00 = base + p * 4 + nb;        o01 = base + p * 4 + nb + 1;
      o10 = base + (p + 10) * 4 + nb; o11 = base + (p + 10) * 4 + nb + 1;
    }
    const float4* a0 = (const float4*)(rowsF + pa0 * RSTRIDE) + (h << 4);
    const float4* a1 = (const float4*)(rowsF + pa1 * RSTRIDE) + (h << 4);
    const float4* b0 = (const float4*)(rowsF + pb0 * RSTRIDE) + (h << 4);
    const float4* b1 = (const float4*)(rowsF + pb1 * RSTRIDE) + (h << 4);
    float4 z = {0.f, 0.f, 0.f, 0.f};
    float4 c00 = z, c01 = z, c10 = z, c11 = z;
    #pragma unroll
    for (int k = 0; k < 16; ++k) {       // immediate-offset ds_read_b128
      float4 av0 = a0[k], av1 = a1[k], bv0 = b0[k], bv1 = b1[k];
      FMA4(c00, av0, bv0); FMA4(c01, av0, bv1);
      FMA4(c10, av1, bv0); FMA4(c11, av1, bv1);
    }
    *o00 = hsum4(c00); *o01 = hsum4(c01);
    *o10 = hsum4(c10); *o11 = hsum4(c11);
  }
  __syncthreads();   // S2: sRp, sGp ready

  // ---- coefficient phase (R5-verified math; k-half combine fused in) ----
  if (t < 35) {
    int aa = 0, bb = 0, cc_ = 0;
    {
      int idx = 0;
      for (int a = 0; a < 5; ++a)
        for (int b = a; b < 5; ++b)
          for (int c = b; c < 5; ++c) {
            if (idx == t) { aa = a; bb = b; cc_ = c; }
            ++idx;
          }
    }
    int vals[3] = {aa, bb, cc_};
    float coeff = 0.f;
    for (int j = 0; j < 3; ++j) {
      int g = vals[j];
      bool dup = false;
      for (int j2 = 0; j2 < j; ++j2) if (vals[j2] == g) dup = true;
      if (dup) continue;
      int u, v;
      if (j == 0)      { u = bb; v = cc_; }
      else if (j == 1) { u = aa; v = cc_; }
      else             { u = aa; v = bb; }
      float s = 0.f;
      for (int mm = 0; mm < 4; ++mm) {
        int au   = (u < 4) ? u * 4 + mm : 16 + mm;
        int au2  = (v < 4) ? v * 4 + mm : 16 + mm;
        int qrow = (g < 4) ? g * 4 + mm : 16 + mm;
        for (int nn = 0; nn < 4; ++nn) {
          int bv1 = (v < 4) ? v * 4 + nn : 16 + nn;
          float kv = sRp[au * 20 + bv1] + sRp[400 + au * 20 + bv1];
          if (u != v) {
            int bv2 = (u < 4) ? u * 4 + nn : 16 + nn;
            kv += sRp[au2 * 20 + bv2] + sRp[400 + au2 * 20 + bv2];
          }
          float gt = sGp[qrow * 4 + nn] + sGp[80 + qrow * 4 + nn];
          s += gt * kv;
        }
      }
      coeff += s;
    }
    sC[t] = coeff;
  } else if (t < 40) {
    int d = t - 35;
    float WUv[4];
    #pragma unroll
    for (int n = 0; n < 4; ++n)
      WUv[n] = sWUp[((n & 1) * 2) * 2 + (n >> 1)] +
               sWUp[((n & 1) * 2 + 1) * 2 + (n >> 1)];
    float s = 0.f;
    if (d < 4) { for (int n = 0; n < 4; ++n) s += WUv[n] * sVSs[d * 4 + n]; }
    else       { for (int n = 0; n < 4; ++n) s += WUv[n] * sVBs[n]; }
    sC2[d] = s;
  } else if (t == 40) {
    sC[35] = 0.f;
  }
  __syncthreads();   // S2b: sC, sC2 ready

  // ---- per-point score: 35-term cubic + 5-term linear (R5-verified) ----
  bool selp = false;
  if (t < P) {
    const int p = t;
    float cc[36];
    #pragma unroll
    for (int j = 0; j < 9; ++j) *(float4*)&cc[4 * j] = ((const float4*)sC)[j];
    float4 c2a = ((const float4*)sC2)[0];
    float c24 = sC2[4];
    float xt[5] = {pv4.x + po4.x, pv4.y + po4.y, pv4.z + po4.z, pv4.w + po4.w, 1.f};
    float t1 = 0.f;
    {
      int idx = 0;
      #pragma unroll
      for (int a = 0; a < 5; ++a) {
        float xa = xt[a];
        #pragma unroll
        for (int b = a; b < 5; ++b) {
          float xab = xa * xt[b];
          #pragma unroll
          for (int c = b; c < 5; ++c) { t1 += cc[idx] * xab * xt[c]; ++idx; }
        }
      }
    }
    float t2 = c24 + xt[0] * c2a.x + xt[1] * c2a.y + xt[2] * c2a.z + xt[3] * c2a.w;
    const float scale = 0.0883883476483184f; // 1/sqrt(128)
    float S = t1 * scale + NEGV * t2 + wb0;
    float sig = 1.f / (1.f + expf(-S));
    float wv = mv ? sig : 0.f;
    wbuf[p] = wv;
    selp = (wv > THRESH) && mv;
    unsigned long long bm = __ballot(selp);
    if ((t & 63) == 0) sBM[t >> 6] = bm;
  }
  __syncthreads();   // S3: wbuf + sel ballots ready

  // ---- selection + write (verified R7 logic) ----
  unsigned long long bm0 = sBM[0], bm1 = sBM[1];
  int cnt = __builtin_popcountll(bm0) + __builtin_popcountll(bm1);
  float* out_pts = out;                       // [NCELL][KSEL][C]
  float* out_w   = out + NCELL * KSEL * C;    // [NCELL][KSEL]

  if (cnt > KSEL) {
    if (t < P) {
      const int p = t;
      float wp = wbuf[p];
      int rank_top = 0;
      for (int q = 0; q < P; ++q) {
        int sq = (int)((q < 64 ? (bm0 >> q) : (bm1 >> (q - 64))) & 1ull);
        if (sq) {
          float wq = wbuf[q];
          if (wq > wp || (wq == wp && q < p)) ++rank_top;
        }
      }
      if (selp && rank_top < KSEL) slotp[rank_top] = p;
    }
    __syncthreads();   // S4: slotp ready
    if (t < KSEL) {
      int p0 = slotp[t];
      ((float4*)out_pts)[cell * KSEL + t] = sPts[p0];
      out_w[cell * KSEL + t] = wbuf[p0];
    }
  } else {
    if (t < KSEL) {
      unsigned long long mm0 = sMM[0], mm1 = sMM[1];
      int fv = mm0 ? __builtin_ctzll(mm0) : (mm1 ? 64 + __builtin_ctzll(mm1) : P);
      float pw = 0.f;
      float4 pvo = {0.f, 0.f, 0.f, 0.f};
      if (cnt == 0) {
        if (t == 0 && fv < P) { pvo = sPts[fv]; pw = wbuf[fv]; }
      } else if (t < cnt) {
        int pc0 = __builtin_popcountll(bm0);
        unsigned long long w; int base, k;
        if (t < pc0) { w = bm0; base = 0; k = t; }
        else         { w = bm1; base = 64; k = t - pc0; }
        for (; k > 0; --k) w &= w - 1;
        int p0 = base + __builtin_ctzll(w);
        pvo = sPts[p0]; pw = wbuf[p0];
      }
      ((float4*)out_pts)[cell * KSEL + t] = pvo;
      out_w[cell * KSEL + t] = pw;
    }
  }
}

extern "C" void kernel_launch(void* const* d_in, const int* in_sizes, int n_in,
                              void* d_out, int out_size, void* d_ws, size_t ws_size,
                              hipStream_t stream) {
  const float* pts  = (const float*)d_in[0];
  const void*  msk  = (const void*)d_in[1];
  const float* pos  = (const float*)d_in[2];
  const float* q_w  = (const float*)d_in[3];
  const float* q_b  = (const float*)d_in[4];
  const float* k_w  = (const float*)d_in[5];
  const float* k_b  = (const float*)d_in[6];
  const float* v_w  = (const float*)d_in[7];
  const float* v_b  = (const float*)d_in[8];
  const float* w_w  = (const float*)d_in[9];
  const float* w_b  = (const float*)d_in[10];
  float* out = (float*)d_out;

  pillar_attn_sample_kernel<<<NCELL, 256, 0, stream>>>(
      pts, msk, pos, q_w, q_b, k_w, k_b, v_w, v_b, w_w, w_b, out);
}

// Round 9
// 9.735 us; speedup vs baseline: 1.9883x; 1.9883x over previous
//
#include <hip/hip_runtime.h>
#include <hip/hip_bf16.h>
#include <math.h>

#define NCELL 32
#define P 128
#define C 4
#define KSEL 64
#define THRESH 0.7f
#define NEGV -1e9f

#define FMA4(acc, av, bv)                                                     \
  acc.x += av.x * bv.x; acc.y += av.y * bv.y;                                 \
  acc.z += av.z * bv.z; acc.w += av.w * bv.w

__device__ __forceinline__ float hsum4(float4 v) {
  return (v.x + v.y) + (v.z + v.w);
}

// fallback row map (stride 132 floats):
//  0..15 K  16..19 KB  20..35 V  36..39 VB  40..55 Q  56..59 QB
// 60..63 WW  64..67 WM  68 ONES
#define RSTRIDE 132
#define NROWS 69

__global__ __launch_bounds__(256) void pillar_attn_sample_kernel(
    const float* __restrict__ pts,      // [NCELL][P][C]
    const void*  __restrict__ maskp,    // [NCELL][P] (dtype sniffed)
    const float* __restrict__ pos,      // [P][C]
    const float* __restrict__ q_w, const float* __restrict__ q_b,
    const float* __restrict__ k_w, const float* __restrict__ k_b,
    const float* __restrict__ v_w, const float* __restrict__ v_b,
    const float* __restrict__ w_w, const float* __restrict__ w_b,
    float* __restrict__ out)            // [NCELL*KSEL*C] ++ [NCELL*KSEL]
{
  // ---- fallback-only LDS (all-masked cell; never touched in common path) ----
  __shared__ __align__(16) float rowsF[NROWS * RSTRIDE];
  __shared__ __align__(16) float sR[400];
  __shared__ __align__(16) float sG[80];
  __shared__ __align__(16) float sVS[32];
  __shared__ float sTrash[28];
  __shared__ float wbuf[P];
  __shared__ int slotp[KSEL];
  // ---- fast-path LDS ----
  __shared__ float sVSs[16];                 // v_w row sums [d][n]
  __shared__ float sVBs[4];                  // v_b row sums [n]
  __shared__ float sWUp[8];                  // WU wave-partials
  // ---- common ----
  __shared__ __align__(16) float4 sPts[P];
  __shared__ unsigned long long sBM[2];      // sel ballots
  __shared__ unsigned long long sMM[2];      // mask ballots

  const int cell = blockIdx.x;
  const int t = threadIdx.x;

  // ---- mask dtype detection (uniform) ----
  int mkind;
  {
    const unsigned* u = (const unsigned*)maskp;
    bool i32ok = true, f32ok = true;
    #pragma unroll
    for (int k = 0; k < 8; ++k) {
      unsigned v = u[k];
      if (v != 0u && v != 1u) i32ok = false;
      if (v != 0u && v != 0x3f800000u) f32ok = false;
    }
    mkind = (i32ok || f32ok) ? 0 : 1;
  }

  // ---- own mask bit (element t&127) ----
  bool mv_self;
  {
    int i = t & 127;
    if (mkind == 0) mv_self = ((const unsigned*)maskp)[cell * P + i] != 0u;
    else            mv_self = ((const unsigned char*)maskp)[cell * P + i] != 0;
  }
  const bool mv = mv_self;

  // ---- early global loads (fast-path working set only) ----
  float4 pv4, po4;
  if (t < P) {
    pv4 = ((const float4*)pts)[cell * P + t];
    po4 = ((const float4*)pos)[t];
  }
  const float4* v4 = (const float4*)v_w;
  float4 v0 = v4[t], v1 = v4[t + 256];
  float ww1 = w_w[t], ww2 = w_w[t + 256];
  float4 vb = {0.f, 0.f, 0.f, 0.f};
  if (t >= 128) vb = ((const float4*)v_b)[t - 128];

  if (t < P) {
    sPts[t] = pv4;
    unsigned long long mm = __ballot(mv);
    if ((t & 63) == 0) sMM[t >> 6] = mm;
  }

  // ---- shuffle reductions: VS (32-groups), VBs, WU (full wave) [R8-verified] ----
  {
    const int w = t >> 6, L = t & 63;
    float s0 = hsum4(v0), s1 = hsum4(v1);
    float u0 = mv_self ? 0.f : ww1, u1 = mv_self ? 0.f : ww2;
    float vbs = (t >= 128) ? hsum4(vb) : 0.f;
    #pragma unroll
    for (int m = 1; m <= 16; m <<= 1) {
      s0 += __shfl_xor(s0, m); s1 += __shfl_xor(s1, m);
    }
    #pragma unroll
    for (int m = 1; m <= 32; m <<= 1) {
      u0 += __shfl_xor(u0, m); u1 += __shfl_xor(u1, m);
    }
    if (t >= 128) {
      #pragma unroll
      for (int m = 1; m <= 16; m <<= 1) vbs += __shfl_xor(vbs, m);
    }
    if ((L & 31) == 0) {
      int half = L >> 5;
      sVSs[2 * w + half]     = s0;
      sVSs[8 + 2 * w + half] = s1;
      if (t >= 128) sVBs[(w - 2) * 2 + half] = vbs;
    }
    if (L == 0) { sWUp[w * 2] = u0; sWUp[w * 2 + 1] = u1; }
  }

  const int allm = __syncthreads_and((int)mv);   // S0 barrier + all-masked flag

  if (allm) {
    // ======== exact fallback: WU==0 => t2==0; full Gram path (17.06-kernel body) ========
    float wb0 = w_b[0];
    {
      const float4* q4 = (const float4*)q_w;
      const float4* k4 = (const float4*)k_w;
      #pragma unroll
      for (int rep = 0; rep < 2; ++rep) {
        int g = t + rep * 256;
        int r = g >> 5, ch = g & 31;
        ((float4*)(rowsF + r * RSTRIDE))[ch] = k4[g];
        ((float4*)(rowsF + (40 + r) * RSTRIDE))[ch] = q4[g];
      }
      { int r = t >> 5, ch = t & 31;
        ((float4*)(rowsF + (20 + r) * RSTRIDE))[ch] = v0; }
      { int g = t + 256; int r = g >> 5, ch = g & 31;
        ((float4*)(rowsF + (20 + r) * RSTRIDE))[ch] = v1; }
      if (t < 128) {
        int r = t >> 5, ch = t & 31;
        ((float4*)(rowsF + (16 + r) * RSTRIDE))[ch] = ((const float4*)k_b)[t];
        ((float4*)(rowsF + (60 + r) * RSTRIDE))[ch] = ((const float4*)w_w)[t];
      } else {
        int u = t - 128; int r = u >> 5, ch = u & 31;
        ((float4*)(rowsF + (36 + r) * RSTRIDE))[ch] = vb;
        ((float4*)(rowsF + (56 + r) * RSTRIDE))[ch] = ((const float4*)q_b)[u];
      }
      rowsF[(64 + (t >> 7)) * RSTRIDE + (t & 127)] = mv_self ? ww1 : 0.f;
      rowsF[(66 + (t >> 7)) * RSTRIDE + (t & 127)] = mv_self ? ww2 : 0.f;
      if (t < 128) rowsF[68 * RSTRIDE + t] = 1.f;
    }
    __syncthreads();

    if (t < 134) {
      int pa0, pa1, pb0, pb1;
      float *o00, *o01, *o10, *o11;
      if (t < 100) {
        int up = t / 10, vq = t % 10;
        pa0 = up;       pa1 = up + 10;
        pb0 = 20 + vq;  pb1 = 30 + vq;
        o00 = &sR[up * 20 + vq];        o01 = &sR[up * 20 + vq + 10];
        o10 = &sR[(up + 10) * 20 + vq]; o11 = &sR[(up + 10) * 20 + vq + 10];
      } else if (t < 120) {
        int e = t - 100;
        int p = e >> 1, nb = (e & 1) * 2;
        pa0 = 40 + p;  pa1 = 50 + p;
        pb0 = 64 + nb; pb1 = 65 + nb;
        o00 = &sG[p * 4 + nb];         o01 = &sG[p * 4 + nb + 1];
        o10 = &sG[(p + 10) * 4 + nb];  o11 = &sG[(p + 10) * 4 + nb + 1];
      } else {
        int e = t - 120;
        int l0 = 2 * e, l1 = 2 * e + 1;
        int r0 = (l0 < 16) ? 20 + l0 : (l0 < 20) ? 36 + (l0 - 16)
               : (l0 < 24) ? 60 + (l0 - 20) : 64 + (l0 - 24);
        int r1 = (l1 < 16) ? 20 + l1 : (l1 < 20) ? 36 + (l1 - 16)
               : (l1 < 24) ? 60 + (l1 - 20) : 64 + (l1 - 24);
        pa0 = 68; pa1 = 68;
        pb0 = r0; pb1 = r1;
        o00 = &sVS[l0]; o01 = &sVS[l1];
        o10 = &sTrash[e]; o11 = &sTrash[e + 14];
      }
      const float4* a0 = (const float4*)(rowsF + pa0 * RSTRIDE);
      const float4* a1 = (const float4*)(rowsF + pa1 * RSTRIDE);
      const float4* b0 = (const float4*)(rowsF + pb0 * RSTRIDE);
      const float4* b1 = (const float4*)(rowsF + pb1 * RSTRIDE);
      float4 z = {0.f, 0.f, 0.f, 0.f};
      float4 c00 = z, c01 = z, c10 = z, c11 = z;
      #pragma unroll
      for (int k = 0; k < 32; ++k) {
        float4 av0 = a0[k], av1 = a1[k], bv0 = b0[k], bv1 = b1[k];
        FMA4(c00, av0, bv0); FMA4(c01, av0, bv1);
        FMA4(c10, av1, bv0); FMA4(c11, av1, bv1);
      }
      *o00 = hsum4(c00); *o01 = hsum4(c01);
      *o10 = hsum4(c10); *o11 = hsum4(c11);
    }
    __syncthreads();

    bool selp = false;
    if (t < P) {
      const int p = t;
      float x[C] = {pv4.x + po4.x, pv4.y + po4.y, pv4.z + po4.z, pv4.w + po4.w};
      float xx[C][C];
      #pragma unroll
      for (int c = 0; c < C; ++c)
        #pragma unroll
        for (int d = 0; d < C; ++d) xx[c][d] = x[c] * x[d];
      const float4* sR4 = (const float4*)sR;
      const float4* sG4 = (const float4*)sG;
      const float4* sVS4 = (const float4*)sVS;
      float t1 = 0.f;
      #pragma unroll
      for (int m = 0; m < 4; ++m) {
        float4 A = sG4[16 + m];
        #pragma unroll
        for (int c = 0; c < C; ++c) {
          float4 gv = sG4[c * 4 + m];
          A.x += x[c] * gv.x; A.y += x[c] * gv.y; A.z += x[c] * gv.z; A.w += x[c] * gv.w;
        }
        float4 Bv = sR4[(16 + m) * 5 + 4];
        #pragma unroll
        for (int c = 0; c < C; ++c) {
          float4 b1v = sR4[(c * 4 + m) * 5 + 4];
          float4 b2v = sR4[(16 + m) * 5 + c];
          Bv.x += x[c] * (b1v.x + b2v.x); Bv.y += x[c] * (b1v.y + b2v.y);
          Bv.z += x[c] * (b1v.z + b2v.z); Bv.w += x[c] * (b1v.w + b2v.w);
        }
        #pragma unroll
        for (int c = 0; c < C; ++c)
          #pragma unroll
          for (int d = 0; d < C; ++d) {
            float4 kv = sR4[(c * 4 + m) * 5 + d];
            float s = xx[c][d];
            Bv.x += s * kv.x; Bv.y += s * kv.y; Bv.z += s * kv.z; Bv.w += s * kv.w;
          }
        t1 += A.x * Bv.x + A.y * Bv.y + A.z * Bv.z + A.w * Bv.w;
      }
      const float scale = 0.0883883476483184f;
      float4 WU4, sv4;
      {
        float4 wws = sVS4[5], wms = sVS4[6];
        WU4.x = wws.x - wms.x; WU4.y = wws.y - wms.y;
        WU4.z = wws.z - wms.z; WU4.w = wws.w - wms.w;
        sv4 = sVS4[4];
        #pragma unroll
        for (int d = 0; d < C; ++d) {
          float4 vs = sVS4[d];
          sv4.x += x[d] * vs.x; sv4.y += x[d] * vs.y;
          sv4.z += x[d] * vs.z; sv4.w += x[d] * vs.w;
        }
      }
      float t2 = WU4.x * sv4.x + WU4.y * sv4.y + WU4.z * sv4.z + WU4.w * sv4.w;
      float S = t1 * scale + NEGV * t2 + wb0;
      float sig = 1.f / (1.f + expf(-S));
      float wv = mv ? sig : 0.f;
      wbuf[p] = wv;
      selp = (wv > THRESH) && mv;
      unsigned long long bm = __ballot(selp);
      if ((t & 63) == 0) sBM[t >> 6] = bm;
    }
    __syncthreads();

    unsigned long long bm0 = sBM[0], bm1 = sBM[1];
    int cnt = __builtin_popcountll(bm0) + __builtin_popcountll(bm1);
    float* out_pts = out;
    float* out_w   = out + NCELL * KSEL * C;
    if (cnt > KSEL) {
      if (t < P) {
        const int p = t;
        float wp = wbuf[p];
        int rank_top = 0;
        for (int q = 0; q < P; ++q) {
          int sq = (int)((q < 64 ? (bm0 >> q) : (bm1 >> (q - 64))) & 1ull);
          if (sq) {
            float wq = wbuf[q];
            if (wq > wp || (wq == wp && q < p)) ++rank_top;
          }
        }
        if (selp && rank_top < KSEL) slotp[rank_top] = p;
      }
      __syncthreads();
      if (t < KSEL) {
        int p0 = slotp[t];
        ((float4*)out_pts)[cell * KSEL + t] = sPts[p0];
        out_w[cell * KSEL + t] = wbuf[p0];
      }
    } else {
      if (t < KSEL) {
        unsigned long long mm0 = sMM[0], mm1 = sMM[1];
        int fv = mm0 ? __builtin_ctzll(mm0) : (mm1 ? 64 + __builtin_ctzll(mm1) : P);
        float pw = 0.f;
        float4 pvo = {0.f, 0.f, 0.f, 0.f};
        if (cnt == 0) {
          if (t == 0 && fv < P) { pvo = sPts[fv]; pw = wbuf[fv]; }
        } else if (t < cnt) {
          int pc0 = __builtin_popcountll(bm0);
          unsigned long long w; int base, k;
          if (t < pc0) { w = bm0; base = 0; k = t; }
          else         { w = bm1; base = 64; k = t - pc0; }
          for (; k > 0; --k) w &= w - 1;
          int p0 = base + __builtin_ctzll(w);
          pvo = sPts[p0]; pw = wbuf[p0];
        }
        ((float4*)out_pts)[cell * KSEL + t] = pvo;
        out_w[cell * KSEL + t] = pw;
      }
    }
    return;
  }

  // ======== fast path: sign(t2) decides everything; weights saturate to 0/1 ========
  bool selp = false;
  if (t < P) {
    float x0 = pv4.x + po4.x, x1 = pv4.y + po4.y;
    float x2 = pv4.z + po4.z, x3 = pv4.w + po4.w;
    float WUv[4];
    #pragma unroll
    for (int n = 0; n < 4; ++n)
      WUv[n] = sWUp[((n & 1) * 2) * 2 + (n >> 1)] +
               sWUp[((n & 1) * 2 + 1) * 2 + (n >> 1)];
    float t2 = 0.f;
    #pragma unroll
    for (int n = 0; n < 4; ++n) {
      float sv = sVBs[n] + x0 * sVSs[0 * 4 + n] + x1 * sVSs[1 * 4 + n]
                         + x2 * sVSs[2 * 4 + n] + x3 * sVSs[3 * 4 + n];
      t2 += WUv[n] * sv;
    }
    selp = (t2 < 0.f) && mv;      // S ≈ -1e9*t2 → sigmoid saturates; w = selp ? 1.0 : 0.0
    unsigned long long bm = __ballot(selp);
    if ((t & 63) == 0) sBM[t >> 6] = bm;
  }
  __syncthreads();   // S1: sel ballots + sPts ready

  // all selected weights == 1.0 exactly => top-k order == ascending index for ANY cnt
  unsigned long long bm0 = sBM[0], bm1 = sBM[1];
  int cnt = __builtin_popcountll(bm0) + __builtin_popcountll(bm1);
  float* out_pts = out;                       // [NCELL][KSEL][C]
  float* out_w   = out + NCELL * KSEL * C;    // [NCELL][KSEL]
  if (t < KSEL) {
    float pw = 0.f;
    float4 pvo = {0.f, 0.f, 0.f, 0.f};
    if (cnt == 0) {
      unsigned long long mm0 = sMM[0], mm1 = sMM[1];
      int fv = mm0 ? __builtin_ctzll(mm0) : (mm1 ? 64 + __builtin_ctzll(mm1) : P);
      if (t == 0 && fv < P) { pvo = sPts[fv]; pw = 0.f; }   // unselected weight == 0.0
    } else if (t < cnt) {
      int pc0 = __builtin_popcountll(bm0);
      unsigned long long w; int base, k;
      if (t < pc0) { w = bm0; base = 0; k = t; }
      else         { w = bm1; base = 64; k = t - pc0; }
      for (; k > 0; --k) w &= w - 1;
      int p0 = base + __builtin_ctzll(w);
      pvo = sPts[p0]; pw = 1.0f;                            // saturated sigmoid
    }
    ((float4*)out_pts)[cell * KSEL + t] = pvo;
    out_w[cell * KSEL + t] = pw;
  }
}

extern "C" void kernel_launch(void* const* d_in, const int* in_sizes, int n_in,
                              void* d_out, int out_size, void* d_ws, size_t ws_size,
                              hipStream_t stream) {
  const float* pts  = (const float*)d_in[0];
  const void*  msk  = (const void*)d_in[1];
  const float* pos  = (const float*)d_in[2];
  const float* q_w  = (const float*)d_in[3];
  const float* q_b  = (const float*)d_in[4];
  const float* k_w  = (const float*)d_in[5];
  const float* k_b  = (const float*)d_in[6];
  const float* v_w  = (const float*)d_in[7];
  const float* v_b  = (const float*)d_in[8];
  const float* w_w  = (const float*)d_in[9];
  const float* w_b  = (const float*)d_in[10];
  float* out = (float*)d_out;

  pillar_attn_sample_kernel<<<NCELL, 256, 0, stream>>>(
      pts, msk, pos, q_w, q_b, k_w, k_b, v_w, v_b, w_w, w_b, out);
}

// Round 10
// 9.695 us; speedup vs baseline: 1.9966x; 1.0041x over previous
//
#include <hip/hip_runtime.h>
#include <hip/hip_bf16.h>
#include <math.h>

#define NCELL 32
#define P 128
#define C 4
#define KSEL 64
#define THRESH 0.7f
#define NEGV -1e9f

#define FMA4(acc, av, bv)                                                     \
  acc.x += av.x * bv.x; acc.y += av.y * bv.y;                                 \
  acc.z += av.z * bv.z; acc.w += av.w * bv.w

__device__ __forceinline__ float hsum4(float4 v) {
  return (v.x + v.y) + (v.z + v.w);
}

// fallback row map (stride 132 floats):
//  0..15 K  16..19 KB  20..35 V  36..39 VB  40..55 Q  56..59 QB
// 60..63 WW  64..67 WM  68 ONES
#define RSTRIDE 132
#define NROWS 69

__global__ __launch_bounds__(256) void pillar_attn_sample_kernel(
    const float* __restrict__ pts,      // [NCELL][P][C]
    const void*  __restrict__ maskp,    // [NCELL][P] (dtype sniffed)
    const float* __restrict__ pos,      // [P][C]
    const float* __restrict__ q_w, const float* __restrict__ q_b,
    const float* __restrict__ k_w, const float* __restrict__ k_b,
    const float* __restrict__ v_w, const float* __restrict__ v_b,
    const float* __restrict__ w_w, const float* __restrict__ w_b,
    float* __restrict__ out)            // [NCELL*KSEL*C] ++ [NCELL*KSEL]
{
  // ---- fallback-only LDS (all-valid cell; untouched in common path) ----
  __shared__ __align__(16) float rowsF[NROWS * RSTRIDE];
  __shared__ __align__(16) float sR[400];
  __shared__ __align__(16) float sG[80];
  __shared__ __align__(16) float sVS[32];
  __shared__ float sTrash[28];
  __shared__ float wbuf[P];
  __shared__ int slotp[KSEL];
  __shared__ __align__(16) float4 sPts[P];
  __shared__ unsigned long long sBM[2];

  const int cell = blockIdx.x;
  const int t = threadIdx.x;

  // ---- mask dtype detection (uniform) ----
  int mkind;
  {
    const unsigned* u = (const unsigned*)maskp;
    bool i32ok = true, f32ok = true;
    #pragma unroll
    for (int k = 0; k < 8; ++k) {
      unsigned v = u[k];
      if (v != 0u && v != 1u) i32ok = false;
      if (v != 0u && v != 0x3f800000u) f32ok = false;
    }
    mkind = (i32ok || f32ok) ? 0 : 1;
  }

  // ---- per-wave mask ballots (identical across waves) ----
  const int L = t & 63;
  bool mb0, mb1;
  if (mkind == 0) {
    const unsigned* mu = (const unsigned*)maskp;
    mb0 = mu[cell * P + L] != 0u;
    mb1 = mu[cell * P + 64 + L] != 0u;
  } else {
    const unsigned char* mc = (const unsigned char*)maskp;
    mb0 = mc[cell * P + L] != 0;
    mb1 = mc[cell * P + 64 + L] != 0;
  }
  const unsigned long long mm0 = __ballot(mb0);
  const unsigned long long mm1 = __ballot(mb1);
  const bool allm = ((mm0 & mm1) == 0xFFFFFFFFFFFFFFFFull);

  float* out_pts = out;                       // [NCELL][KSEL][C]
  float* out_w   = out + NCELL * KSEL * C;    // [NCELL][KSEL]

  if (!allm) {
    // ======== fast path: wave 0 only, zero barriers, zero LDS ========
    if (t >= 64) return;
    const float4* p4 = (const float4*)pts;
    const float4* s4 = (const float4*)pos;
    float4 pa = p4[cell * P + L],      oa = s4[L];
    float4 pb = p4[cell * P + 64 + L], ob = s4[64 + L];

    // v_w row sums: lane L's 8 float4 all lie in Gram row r = L>>2
    const float4* v4 = (const float4*)v_w;
    float vp = 0.f;
    #pragma unroll
    for (int j = 0; j < 8; ++j) vp += hsum4(v4[L * 8 + j]);
    vp += __shfl_xor(vp, 1); vp += __shfl_xor(vp, 2);
    float VSv[16];
    #pragma unroll
    for (int r = 0; r < 16; ++r) VSv[r] = __shfl(vp, r << 2);

    // v_b row sums: lane's 2 float4 in row n = L>>4
    const float4* b4 = (const float4*)v_b;
    float bp = hsum4(b4[2 * L]) + hsum4(b4[2 * L + 1]);
    bp += __shfl_xor(bp, 1); bp += __shfl_xor(bp, 2);
    bp += __shfl_xor(bp, 4); bp += __shfl_xor(bp, 8);

    // WU[n] = sum of w_w[n][i] over UNMASKED i, via ballot bit tests
    const float4* w4 = (const float4*)w_w;
    float4 wA = w4[2 * L], wB = w4[2 * L + 1];
    float up = 0.f;
    {
      float wv[8] = {wA.x, wA.y, wA.z, wA.w, wB.x, wB.y, wB.z, wB.w};
      int i0 = (L << 3) & 127;
      #pragma unroll
      for (int j = 0; j < 8; ++j) {
        int i = i0 + j;
        unsigned long long bit = (i < 64) ? (mm0 >> i) : (mm1 >> (i - 64));
        if (!(bit & 1ull)) up += wv[j];
      }
    }
    up += __shfl_xor(up, 1); up += __shfl_xor(up, 2);
    up += __shfl_xor(up, 4); up += __shfl_xor(up, 8);

    float WUv[4], VBv[4];
    #pragma unroll
    for (int n = 0; n < 4; ++n) {
      WUv[n] = __shfl(up, n << 4);
      VBv[n] = __shfl(bp, n << 4);
    }

    // t2 sign decides selection (sigmoid saturates to exact 0/1)
    float t2a = 0.f, t2b = 0.f;
    {
      float x0 = pa.x + oa.x, x1 = pa.y + oa.y, x2 = pa.z + oa.z, x3 = pa.w + oa.w;
      #pragma unroll
      for (int n = 0; n < 4; ++n) {
        float sv = VBv[n] + x0 * VSv[n] + x1 * VSv[4 + n]
                          + x2 * VSv[8 + n] + x3 * VSv[12 + n];
        t2a += WUv[n] * sv;
      }
    }
    {
      float x0 = pb.x + ob.x, x1 = pb.y + ob.y, x2 = pb.z + ob.z, x3 = pb.w + ob.w;
      #pragma unroll
      for (int n = 0; n < 4; ++n) {
        float sv = VBv[n] + x0 * VSv[n] + x1 * VSv[4 + n]
                          + x2 * VSv[8 + n] + x3 * VSv[12 + n];
        t2b += WUv[n] * sv;
      }
    }
    bool sel0 = (t2a < 0.f) && mb0;
    bool sel1 = (t2b < 0.f) && mb1;
    unsigned long long bm0 = __ballot(sel0);
    unsigned long long bm1 = __ballot(sel1);
    int cnt = __builtin_popcountll(bm0) + __builtin_popcountll(bm1);

    // all selected weights == 1.0 => order == ascending index for ANY cnt
    float pw = 0.f;
    float4 pvo = {0.f, 0.f, 0.f, 0.f};
    if (cnt == 0) {
      int fv = mm0 ? __builtin_ctzll(mm0) : (mm1 ? 64 + __builtin_ctzll(mm1) : P);
      if (L == 0 && fv < P) { pvo = p4[cell * P + fv]; pw = 0.f; }
    } else if (L < cnt) {
      int pc0 = __builtin_popcountll(bm0);
      unsigned long long w; int base, k;
      if (L < pc0) { w = bm0; base = 0; k = L; }
      else         { w = bm1; base = 64; k = L - pc0; }
      for (; k > 0; --k) w &= w - 1;
      int p0 = base + __builtin_ctzll(w);
      pvo = p4[cell * P + p0]; pw = 1.0f;
    }
    ((float4*)out_pts)[cell * KSEL + L] = pvo;
    out_w[cell * KSEL + L] = pw;
    return;
  }

  // ======== exact fallback: all points valid => WU==0, t2==0; full Gram path ========
  const bool mv = ((t >> 6) & 1) ? mb1 : mb0;   // own mask bit for element t&127 (true here)
  float4 pv4, po4;
  if (t < P) {
    pv4 = ((const float4*)pts)[cell * P + t];
    po4 = ((const float4*)pos)[t];
    sPts[t] = pv4;
  }
  const float4* v4f = (const float4*)v_w;
  float4 v0 = v4f[t], v1 = v4f[t + 256];
  float ww1 = w_w[t], ww2 = w_w[t + 256];
  float4 vb = {0.f, 0.f, 0.f, 0.f};
  if (t >= 128) vb = ((const float4*)v_b)[t - 128];
  float wb0 = w_b[0];
  {
    const float4* q4 = (const float4*)q_w;
    const float4* k4 = (const float4*)k_w;
    #pragma unroll
    for (int rep = 0; rep < 2; ++rep) {
      int g = t + rep * 256;
      int r = g >> 5, ch = g & 31;
      ((float4*)(rowsF + r * RSTRIDE))[ch] = k4[g];
      ((float4*)(rowsF + (40 + r) * RSTRIDE))[ch] = q4[g];
    }
    { int r = t >> 5, ch = t & 31;
      ((float4*)(rowsF + (20 + r) * RSTRIDE))[ch] = v0; }
    { int g = t + 256; int r = g >> 5, ch = g & 31;
      ((float4*)(rowsF + (20 + r) * RSTRIDE))[ch] = v1; }
    if (t < 128) {
      int r = t >> 5, ch = t & 31;
      ((float4*)(rowsF + (16 + r) * RSTRIDE))[ch] = ((const float4*)k_b)[t];
      ((float4*)(rowsF + (60 + r) * RSTRIDE))[ch] = ((const float4*)w_w)[t];
    } else {
      int u = t - 128; int r = u >> 5, ch = u & 31;
      ((float4*)(rowsF + (36 + r) * RSTRIDE))[ch] = vb;
      ((float4*)(rowsF + (56 + r) * RSTRIDE))[ch] = ((const float4*)q_b)[u];
    }
    rowsF[(64 + (t >> 7)) * RSTRIDE + (t & 127)] = mv ? ww1 : 0.f;
    rowsF[(66 + (t >> 7)) * RSTRIDE + (t & 127)] = mv ? ww2 : 0.f;
    if (t < 128) rowsF[68 * RSTRIDE + t] = 1.f;
  }
  __syncthreads();

  if (t < 134) {
    int pa0, pa1, pb0, pb1;
    float *o00, *o01, *o10, *o11;
    if (t < 100) {
      int up = t / 10, vq = t % 10;
      pa0 = up;       pa1 = up + 10;
      pb0 = 20 + vq;  pb1 = 30 + vq;
      o00 = &sR[up * 20 + vq];        o01 = &sR[up * 20 + vq + 10];
      o10 = &sR[(up + 10) * 20 + vq]; o11 = &sR[(up + 10) * 20 + vq + 10];
    } else if (t < 120) {
      int e = t - 100;
      int p = e >> 1, nb = (e & 1) * 2;
      pa0 = 40 + p;  pa1 = 50 + p;
      pb0 = 64 + nb; pb1 = 65 + nb;
      o00 = &sG[p * 4 + nb];         o01 = &sG[p * 4 + nb + 1];
      o10 = &sG[(p + 10) * 4 + nb];  o11 = &sG[(p + 10) * 4 + nb + 1];
    } else {
      int e = t - 120;
      int l0 = 2 * e, l1 = 2 * e + 1;
      int r0 = (l0 < 16) ? 20 + l0 : (l0 < 20) ? 36 + (l0 - 16)
             : (l0 < 24) ? 60 + (l0 - 20) : 64 + (l0 - 24);
      int r1 = (l1 < 16) ? 20 + l1 : (l1 < 20) ? 36 + (l1 - 16)
             : (l1 < 24) ? 60 + (l1 - 20) : 64 + (l1 - 24);
      pa0 = 68; pa1 = 68;
      pb0 = r0; pb1 = r1;
      o00 = &sVS[l0]; o01 = &sVS[l1];
      o10 = &sTrash[e]; o11 = &sTrash[e + 14];
    }
    const float4* a0 = (const float4*)(rowsF + pa0 * RSTRIDE);
    const float4* a1 = (const float4*)(rowsF + pa1 * RSTRIDE);
    const float4* b0 = (const float4*)(rowsF + pb0 * RSTRIDE);
    const float4* b1 = (const float4*)(rowsF + pb1 * RSTRIDE);
    float4 z = {0.f, 0.f, 0.f, 0.f};
    float4 c00 = z, c01 = z, c10 = z, c11 = z;
    #pragma unroll
    for (int k = 0; k < 32; ++k) {
      float4 av0 = a0[k], av1 = a1[k], bv0 = b0[k], bv1 = b1[k];
      FMA4(c00, av0, bv0); FMA4(c01, av0, bv1);
      FMA4(c10, av1, bv0); FMA4(c11, av1, bv1);
    }
    *o00 = hsum4(c00); *o01 = hsum4(c01);
    *o10 = hsum4(c10); *o11 = hsum4(c11);
  }
  __syncthreads();

  bool selp = false;
  if (t < P) {
    const int p = t;
    float x[C] = {pv4.x + po4.x, pv4.y + po4.y, pv4.z + po4.z, pv4.w + po4.w};
    float xx[C][C];
    #pragma unroll
    for (int c = 0; c < C; ++c)
      #pragma unroll
      for (int d = 0; d < C; ++d) xx[c][d] = x[c] * x[d];
    const float4* sR4 = (const float4*)sR;
    const float4* sG4 = (const float4*)sG;
    const float4* sVS4 = (const float4*)sVS;
    float t1 = 0.f;
    #pragma unroll
    for (int m = 0; m < 4; ++m) {
      float4 A = sG4[16 + m];
      #pragma unroll
      for (int c = 0; c < C; ++c) {
        float4 gv = sG4[c * 4 + m];
        A.x += x[c] * gv.x; A.y += x[c] * gv.y; A.z += x[c] * gv.z; A.w += x[c] * gv.w;
      }
      float4 Bv = sR4[(16 + m) * 5 + 4];
      #pragma unroll
      for (int c = 0; c < C; ++c) {
        float4 b1v = sR4[(c * 4 + m) * 5 + 4];
        float4 b2v = sR4[(16 + m) * 5 + c];
        Bv.x += x[c] * (b1v.x + b2v.x); Bv.y += x[c] * (b1v.y + b2v.y);
        Bv.z += x[c] * (b1v.z + b2v.z); Bv.w += x[c] * (b1v.w + b2v.w);
      }
      #pragma unroll
      for (int c = 0; c < C; ++c)
        #pragma unroll
        for (int d = 0; d < C; ++d) {
          float4 kv = sR4[(c * 4 + m) * 5 + d];
          float s = xx[c][d];
          Bv.x += s * kv.x; Bv.y += s * kv.y; Bv.z += s * kv.z; Bv.w += s * kv.w;
        }
      t1 += A.x * Bv.x + A.y * Bv.y + A.z * Bv.z + A.w * Bv.w;
    }
    const float scale = 0.0883883476483184f;
    float4 WU4, sv4;
    {
      float4 wws = sVS4[5], wms = sVS4[6];
      WU4.x = wws.x - wms.x; WU4.y = wws.y - wms.y;
      WU4.z = wws.z - wms.z; WU4.w = wws.w - wms.w;
      sv4 = sVS4[4];
      #pragma unroll
      for (int d = 0; d < C; ++d) {
        float4 vs = sVS4[d];
        sv4.x += x[d] * vs.x; sv4.y += x[d] * vs.y;
        sv4.z += x[d] * vs.z; sv4.w += x[d] * vs.w;
      }
    }
    float t2 = WU4.x * sv4.x + WU4.y * sv4.y + WU4.z * sv4.z + WU4.w * sv4.w;
    float S = t1 * scale + NEGV * t2 + wb0;
    float sig = 1.f / (1.f + expf(-S));
    float wv = mv ? sig : 0.f;
    wbuf[p] = wv;
    selp = (wv > THRESH) && mv;
    unsigned long long bm = __ballot(selp);
    if ((t & 63) == 0) sBM[t >> 6] = bm;
  }
  __syncthreads();

  unsigned long long bm0 = sBM[0], bm1 = sBM[1];
  int cnt = __builtin_popcountll(bm0) + __builtin_popcountll(bm1);
  if (cnt > KSEL) {
    if (t < P) {
      const int p = t;
      float wp = wbuf[p];
      int rank_top = 0;
      for (int q = 0; q < P; ++q) {
        int sq = (int)((q < 64 ? (bm0 >> q) : (bm1 >> (q - 64))) & 1ull);
        if (sq) {
          float wq = wbuf[q];
          if (wq > wp || (wq == wp && q < p)) ++rank_top;
        }
      }
      if (selp && rank_top < KSEL) slotp[rank_top] = p;
    }
    __syncthreads();
    if (t < KSEL) {
      int p0 = slotp[t];
      ((float4*)out_pts)[cell * KSEL + t] = sPts[p0];
      out_w[cell * KSEL + t] = wbuf[p0];
    }
  } else {
    if (t < KSEL) {
      int fv = mm0 ? __builtin_ctzll(mm0) : (mm1 ? 64 + __builtin_ctzll(mm1) : P);
      float pw = 0.f;
      float4 pvo = {0.f, 0.f, 0.f, 0.f};
      if (cnt == 0) {
        if (t == 0 && fv < P) { pvo = sPts[fv]; pw = wbuf[fv]; }
      } else if (t < cnt) {
        int pc0 = __builtin_popcountll(bm0);
        unsigned long long w; int base, k;
        if (t < pc0) { w = bm0; base = 0; k = t; }
        else         { w = bm1; base = 64; k = t - pc0; }
        for (; k > 0; --k) w &= w - 1;
        int p0 = base + __builtin_ctzll(w);
        pvo = sPts[p0]; pw = wbuf[p0];
      }
      ((float4*)out_pts)[cell * KSEL + t] = pvo;
      out_w[cell * KSEL + t] = pw;
    }
  }
}

extern "C" void kernel_launch(void* const* d_in, const int* in_sizes, int n_in,
                              void* d_out, int out_size, void* d_ws, size_t ws_size,
                              hipStream_t stream) {
  const float* pts  = (const float*)d_in[0];
  const void*  msk  = (const void*)d_in[1];
  const float* pos  = (const float*)d_in[2];
  const float* q_w  = (const float*)d_in[3];
  const float* q_b  = (const float*)d_in[4];
  const float* k_w  = (const float*)d_in[5];
  const float* k_b  = (const float*)d_in[6];
  const float* v_w  = (const float*)d_in[7];
  const float* v_b  = (const float*)d_in[8];
  const float* w_w  = (const float*)d_in[9];
  const float* w_b  = (const float*)d_in[10];
  float* out = (float*)d_out;

  pillar_attn_sample_kernel<<<NCELL, 256, 0, stream>>>(
      pts, msk, pos, q_w, q_b, k_w, k_b, v_w, v_b, w_w, w_b, out);
}